// Round 5
// baseline (524.451 us; speedup 1.0000x reference)
//
#include <hip/hip_runtime.h>

#define H 128
#define W 128
#define C 128
#define NB 4
#define HW (H * W)
#define PXB 32            // pixels per block (quarter row)
#define NSEG (W / PXB)    // 4
#define TPX 64            // pixels per transpose block

// ---------------------------------------------------------------------------
// Pre-pass 1: NCHW -> NHWC transpose of x into workspace (32 MB).
// ---------------------------------------------------------------------------
__global__ __launch_bounds__(256) void transpose_nchw_nhwc(
    const float* __restrict__ x, float* __restrict__ xt) {
  __shared__ float tile[TPX][C + 1];  // 64 x 129 floats = 33 KB
  const int blk = blockIdx.x;
  const int n = blk >> 8;                 // HW/TPX = 256 blocks per image
  const int p0 = (blk & 255) * TPX;
  const float* xn = x + (size_t)n * C * HW;
  float* xtn = xt + (size_t)n * HW * C;

  const int i = threadIdx.x & 63;         // pixel within tile
  const int c0 = threadIdx.x >> 6;        // 0..3
#pragma unroll
  for (int c = c0; c < C; c += 4)
    tile[i][c] = xn[(size_t)c * HW + p0 + i];
  __syncthreads();

  const int cl = threadIdx.x & 31;        // channel quad 0..31
  const int pr = threadIdx.x >> 5;        // 0..7
#pragma unroll
  for (int p = pr; p < TPX; p += 8) {
    float4 v = make_float4(tile[p][4 * cl + 0], tile[p][4 * cl + 1],
                           tile[p][4 * cl + 2], tile[p][4 * cl + 3]);
    *(float4*)(xtn + (size_t)(p0 + p) * C + 4 * cl) = v;
  }
}

// ---------------------------------------------------------------------------
// Pre-pass 2: weight re-layout wg[p][ch][k] -> wt[ch][k][p]  (9216 floats).
// ---------------------------------------------------------------------------
__global__ __launch_bounds__(256) void prep_wt(
    const float* __restrict__ wg, float* __restrict__ wt) {
  const int i = blockIdx.x * 256 + threadIdx.x;  // 36 blocks x 256 = 9216
  const int ch = i / 72;
  const int rem = i % 72;
  const int k = rem >> 3;
  const int p = rem & 7;
  wt[i] = wg[((size_t)p * C + ch) * 9 + k];
}

// ---------------------------------------------------------------------------
// Fused deformable-conv v5.
//  - Phase 1: weights staged to LDS (two 64-ch halves, stride 76), 4ch/thread,
//    in-wave shfl_xor reduce (round-4 phase 1, which was correct).
//  - Phase 2: gather thread layout == store layout: thread (px-pair, quad,
//    kh-half) computes a 2x2 output block for its 4 channels directly.
//    -> no LDS restage, ZERO phase-2 barriers, float4 stores (full lines).
//  - Single aliased 19.5 KB LDS buffer; explicit barriers between lifetimes.
// Region map of lshu (float offsets):
//   [0,4864)   conv weights (64ch half, stride 76)   -- dead after conv
//   [0,1152)   lacc2[4][32][9] per-wave partials      -- after conv, +barrier
//   [1152,1440) loff[32][9] final offsets
//   [1536,2560) ltapi[32][4] int4 tap indices
//   [2560,3584) ltapw[32][4] float4 tap weights
// ---------------------------------------------------------------------------
__global__ __launch_bounds__(256, 4) void dcn_fused_t5(
    const float* __restrict__ xt, const float* __restrict__ wt,
    const float* __restrict__ b, float* __restrict__ out) {

  __shared__ __align__(16) float lshu[4864];  // 19456 B total

  const int t = threadIdx.x;
  const int bxr = blockIdx.x;
  const int bx = ((bxr & 7) << 8) | (bxr >> 3);  // XCD swizzle (2048 = 8*256)
  const int seg = bx & (NSEG - 1);
  const int y = (bx >> 2) & (H - 1);
  const int n = bx >> 9;
  const int x0 = seg * PXB;

  const float* xtn = xt + (size_t)n * HW * C;

  // ---------------- Phase 1: offset conv, weights from LDS -----------------
  {
    const int pp = t & 15;   // pixel pair -> pixels x0+2pp, x0+2pp+1
    const int cg = t >> 4;   // channel group 0..15 (4 ch per half each)
    const int xb = x0 + 2 * pp;

    int xs[4];
    float colm[4];
#pragma unroll
    for (int j = 0; j < 4; ++j) {
      int xa = xb - 1 + j;
      colm[j] = ((unsigned)xa < (unsigned)W) ? 1.f : 0.f;
      xs[j] = xa < 0 ? 0 : (xa > W - 1 ? W - 1 : xa);
    }
    int pix[3][4];
    float m[3][4];
#pragma unroll
    for (int r = 0; r < 3; ++r) {
      int yy = y + r - 1;
      float rm = ((unsigned)yy < (unsigned)H) ? 1.f : 0.f;
      int yc = yy < 0 ? 0 : (yy > H - 1 ? H - 1 : yy);
#pragma unroll
      for (int j = 0; j < 4; ++j) {
        m[r][j] = rm * colm[j];
        pix[r][j] = yc * W + xs[j];
      }
    }

    float acc[2][8];
#pragma unroll
    for (int p = 0; p < 8; ++p) { acc[0][p] = 0.f; acc[1][p] = 0.f; }

    const float4* wt4 = (const float4*)wt;

#pragma unroll
    for (int h = 0; h < 2; ++h) {
      if (h) __syncthreads();  // WAR: previous half's LDS reads done
      // stage 64 channels of weights: 1152 float4 compact -> stride 76
#pragma unroll
      for (int i = 0; i < 5; ++i) {
        int idx = t + 256 * i;
        if (idx < 1152) {
          int chl = idx / 18;
          int j = idx - chl * 18;
          *(float4*)&lshu[chl * 76 + j * 4] = wt4[h * 1152 + idx];
        }
      }
      __syncthreads();

      // 12 window pixels x 4 channels (one float4 each)
      const int cb4 = h * 16 + cg;  // float4 column within 128-ch row
      float xvq[3][4][4];
#pragma unroll
      for (int r = 0; r < 3; ++r) {
#pragma unroll
        for (int j = 0; j < 4; ++j) {
          float4 v = *(const float4*)(xtn + (size_t)pix[r][j] * C + cb4 * 4);
          const float mm = m[r][j];
          xvq[r][j][0] = v.x * mm;
          xvq[r][j][1] = v.y * mm;
          xvq[r][j][2] = v.z * mm;
          xvq[r][j][3] = v.w * mm;
        }
      }
#pragma unroll
      for (int cc = 0; cc < 4; ++cc) {
        const int chl = cg * 4 + cc;
        const float* wr = &lshu[chl * 76];
#pragma unroll
        for (int k = 0; k < 9; ++k) {
          const int r = k / 3, kw = k % 3;
          const float4 wa = *(const float4*)&wr[k * 8];      // p = 0..3
          const float4 wb = *(const float4*)&wr[k * 8 + 4];  // p = 4..7
          const float xl = xvq[r][kw][cc];
          const float xr = xvq[r][kw + 1][cc];
          acc[0][0] += xl * wa.x; acc[0][1] += xl * wa.y;
          acc[0][2] += xl * wa.z; acc[0][3] += xl * wa.w;
          acc[0][4] += xl * wb.x; acc[0][5] += xl * wb.y;
          acc[0][6] += xl * wb.z; acc[0][7] += xl * wb.w;
          acc[1][0] += xr * wa.x; acc[1][1] += xr * wa.y;
          acc[1][2] += xr * wa.z; acc[1][3] += xr * wa.w;
          acc[1][4] += xr * wb.x; acc[1][5] += xr * wb.y;
          acc[1][6] += xr * wb.z; acc[1][7] += xr * wb.w;
        }
      }
    }

    // In-wave butterfly reduce over the wave's 4 channel-groups.
#pragma unroll
    for (int u = 0; u < 2; ++u) {
#pragma unroll
      for (int p = 0; p < 8; ++p) {
        acc[u][p] += __shfl_xor(acc[u][p], 16);
        acc[u][p] += __shfl_xor(acc[u][p], 32);
      }
    }
    __syncthreads();  // all weight reads done before lacc2 aliases the region
    if ((t & 63) < 16) {
      const int wv = t >> 6;  // wave 0..3
#pragma unroll
      for (int p = 0; p < 8; ++p) {
        lshu[wv * 288 + (2 * pp) * 9 + p] = acc[0][p];
        lshu[wv * 288 + (2 * pp + 1) * 9 + p] = acc[1][p];
      }
    }
  }
  __syncthreads();

  // ---------------- Phase 1.5: reduce 4 waves + bias -----------------------
  {
    const int px = t >> 3;  // 0..31
    const int p = t & 7;
    lshu[1152 + px * 9 + p] =
        b[p] + lshu[0 * 288 + px * 9 + p] + lshu[1 * 288 + px * 9 + p] +
        lshu[2 * 288 + px * 9 + p] + lshu[3 * 288 + px * 9 + p];
  }
  __syncthreads();

  // ---------------- Phase 1.75: per (px,pos) tap table ---------------------
  if (t < 128) {
    const int px = t >> 2;
    const int pos = t & 3;
    const int xx = x0 + px;
    float sy = (float)y + lshu[1152 + px * 9 + 2 * pos];
    float sx = (float)xx + lshu[1152 + px * 9 + 2 * pos + 1];
    float y0f = floorf(sy), x0f = floorf(sx);
    float wy1 = sy - y0f, wx1 = sx - x0f;
    float wy0 = 1.f - wy1, wx0 = 1.f - wx1;
    int iy0 = (int)y0f, ix0 = (int)x0f;
    int iy1 = iy0 + 1, ix1 = ix0 + 1;
    float vy0 = ((unsigned)iy0 < (unsigned)H) ? 1.f : 0.f;
    float vy1 = ((unsigned)iy1 < (unsigned)H) ? 1.f : 0.f;
    float vx0 = ((unsigned)ix0 < (unsigned)W) ? 1.f : 0.f;
    float vx1 = ((unsigned)ix1 < (unsigned)W) ? 1.f : 0.f;
    int cy0 = iy0 < 0 ? 0 : (iy0 > H - 1 ? H - 1 : iy0);
    int cy1 = iy1 < 0 ? 0 : (iy1 > H - 1 ? H - 1 : iy1);
    int cx0 = ix0 < 0 ? 0 : (ix0 > W - 1 ? W - 1 : ix0);
    int cx1 = ix1 < 0 ? 0 : (ix1 > W - 1 ? W - 1 : ix1);
    *(int4*)&lshu[1536 + (px * 4 + pos) * 4] =
        make_int4(cy0 * W + cx0, cy0 * W + cx1, cy1 * W + cx0, cy1 * W + cx1);
    *(float4*)&lshu[2560 + (px * 4 + pos) * 4] =
        make_float4(wy0 * wx0 * vy0 * vx0, wy0 * wx1 * vy0 * vx1,
                    wy1 * wx0 * vy1 * vx0, wy1 * wx1 * vy1 * vx1);
  }
  __syncthreads();

  // ---------------- Phase 2: direct gather -> 2x2 float4 stores ------------
  // Thread (pair, q, half): px pair {2pair, 2pair+1} of the pass, channel
  // quad q (channels 4q..4q+3), kh = half. 4 combos x 4 taps gathered
  // channel-major; output written as one float4 per channel (full 2x2-kw row).
  // No barriers, no LDS restage.
  {
    const int pair = t & 3;
    const int q = (t >> 2) & 31;
    const int half = t >> 7;
    const int pos0 = 2 * half;
    const float4* xt4 = (const float4*)xtn;
    const int4* ltapi4 = (const int4*)&lshu[1536];
    const float4* ltapw4 = (const float4*)&lshu[2560];
    float* outn = out + (size_t)n * C * (4 * HW);

#pragma unroll 1
    for (int pass = 0; pass < 4; ++pass) {
      const int px0 = pass * 8 + 2 * pair;
      float sc[2][2][4];
#pragma unroll
      for (int bb = 0; bb < 2; ++bb) {
#pragma unroll
        for (int pp2 = 0; pp2 < 2; ++pp2) {
          const int idx = (px0 + bb) * 4 + pos0 + pp2;
          const int4 o = ltapi4[idx];
          const float4 wv = ltapw4[idx];
          const float4 v00 = xt4[(size_t)o.x * (C / 4) + q];
          const float4 v01 = xt4[(size_t)o.y * (C / 4) + q];
          const float4 v10 = xt4[(size_t)o.z * (C / 4) + q];
          const float4 v11 = xt4[(size_t)o.w * (C / 4) + q];
          sc[bb][pp2][0] = wv.x * v00.x + wv.y * v01.x + wv.z * v10.x + wv.w * v11.x;
          sc[bb][pp2][1] = wv.x * v00.y + wv.y * v01.y + wv.z * v10.y + wv.w * v11.y;
          sc[bb][pp2][2] = wv.x * v00.z + wv.y * v01.z + wv.z * v10.z + wv.w * v11.z;
          sc[bb][pp2][3] = wv.x * v00.w + wv.y * v01.w + wv.z * v10.w + wv.w * v11.w;
        }
      }
      // store: one float4 per channel, row 2y+half, cols 2*(x0+px0)..+3
      float* obase = outn + (size_t)(2 * y + half) * (2 * W) + 2 * (x0 + px0);
#pragma unroll
      for (int j = 0; j < 4; ++j) {
        *(float4*)(obase + (size_t)(4 * q + j) * (4 * HW)) =
            make_float4(sc[0][0][j], sc[0][1][j], sc[1][0][j], sc[1][1][j]);
      }
    }
  }
}

// ---------------------------------------------------------------------------
// Fallback: original NCHW-gather kernel (used only if workspace too small).
// ---------------------------------------------------------------------------
__global__ __launch_bounds__(256) void dcn_fused(
    const float* __restrict__ x, const float* __restrict__ wg,
    const float* __restrict__ b, float* __restrict__ out) {

  __shared__ float lacc[16][PXB][8];
  __shared__ float loff[PXB][9];

  const int t = threadIdx.x;
  const int bx = blockIdx.x;
  const int seg = bx & (NSEG - 1);
  const int y = (bx >> 2) & (H - 1);
  const int n = bx >> 9;
  const int x0 = seg * PXB;

  const float* xn = x + (size_t)n * C * HW;

  {
    const int pp = t & 15;
    const int cg = t >> 4;
    const int xb = x0 + 2 * pp;

    int xs[4];
    float colm[4];
#pragma unroll
    for (int j = 0; j < 4; ++j) {
      int xa = xb - 1 + j;
      colm[j] = ((unsigned)xa < (unsigned)W) ? 1.f : 0.f;
      xs[j] = xa < 0 ? 0 : (xa > W - 1 ? W - 1 : xa);
    }
    int rowo[3];
    float m[3][4];
#pragma unroll
    for (int r = 0; r < 3; ++r) {
      int yy = y + r - 1;
      float rm = ((unsigned)yy < (unsigned)H) ? 1.f : 0.f;
      int yc = yy < 0 ? 0 : (yy > H - 1 ? H - 1 : yy);
      rowo[r] = yc * W;
#pragma unroll
      for (int j = 0; j < 4; ++j) m[r][j] = rm * colm[j];
    }

    float acc[2][8];
#pragma unroll
    for (int p = 0; p < 8; ++p) { acc[0][p] = 0.f; acc[1][p] = 0.f; }

    for (int c = 0; c < 8; ++c) {
      const int ch = cg * 8 + c;
      const float* xc = xn + (size_t)ch * HW;
      float xv[3][4];
#pragma unroll
      for (int r = 0; r < 3; ++r)
#pragma unroll
        for (int j = 0; j < 4; ++j)
          xv[r][j] = xc[rowo[r] + xs[j]] * m[r][j];

      const float* wc = wg + (size_t)ch * 9;
#pragma unroll
      for (int p = 0; p < 8; ++p) {
        const float* wp = wc + (size_t)p * C * 9;
#pragma unroll
        for (int r = 0; r < 3; ++r) {
#pragma unroll
          for (int kw = 0; kw < 3; ++kw) {
            const float wv = wp[r * 3 + kw];
            acc[0][p] += xv[r][kw] * wv;
            acc[1][p] += xv[r][kw + 1] * wv;
          }
        }
      }
    }
#pragma unroll
    for (int p = 0; p < 8; ++p) {
      lacc[cg][2 * pp][p] = acc[0][p];
      lacc[cg][2 * pp + 1][p] = acc[1][p];
    }
  }
  __syncthreads();

  {
    const int px = t >> 3;
    const int p = t & 7;
    float s = b[p];
#pragma unroll
    for (int g = 0; g < 16; ++g) s += lacc[g][px][p];
    loff[px][p] = s;
  }
  __syncthreads();

  {
    const int px = t & (PXB - 1);
    const int sg = t >> 5;
    const int xx = x0 + px;

    float offv[8];
#pragma unroll
    for (int q = 0; q < 8; ++q) offv[q] = loff[px][q];

    int o00[4], o01[4], o10[4], o11[4];
    float w00[4], w01[4], w10[4], w11[4];
#pragma unroll
    for (int p = 0; p < 4; ++p) {
      float sy = (float)y + offv[2 * p];
      float sx = (float)xx + offv[2 * p + 1];
      float y0f = floorf(sy), x0f = floorf(sx);
      float wy1 = sy - y0f, wx1 = sx - x0f;
      float wy0 = 1.f - wy1, wx0 = 1.f - wx1;
      int iy0 = (int)y0f, ix0 = (int)x0f;
      int iy1 = iy0 + 1, ix1 = ix0 + 1;
      float vy0 = ((unsigned)iy0 < (unsigned)H) ? 1.f : 0.f;
      float vy1 = ((unsigned)iy1 < (unsigned)H) ? 1.f : 0.f;
      float vx0 = ((unsigned)ix0 < (unsigned)W) ? 1.f : 0.f;
      float vx1 = ((unsigned)ix1 < (unsigned)W) ? 1.f : 0.f;
      int cy0 = iy0 < 0 ? 0 : (iy0 > H - 1 ? H - 1 : iy0);
      int cy1 = iy1 < 0 ? 0 : (iy1 > H - 1 ? H - 1 : iy1);
      int cx0 = ix0 < 0 ? 0 : (ix0 > W - 1 ? W - 1 : ix0);
      int cx1 = ix1 < 0 ? 0 : (ix1 > W - 1 ? W - 1 : ix1);
      o00[p] = cy0 * W + cx0; o01[p] = cy0 * W + cx1;
      o10[p] = cy1 * W + cx0; o11[p] = cy1 * W + cx1;
      w00[p] = wy0 * wx0 * vy0 * vx0;
      w01[p] = wy0 * wx1 * vy0 * vx1;
      w10[p] = wy1 * wx0 * vy1 * vx0;
      w11[p] = wy1 * wx1 * vy1 * vx1;
    }

    float* outn = out + (size_t)n * C * (2 * H) * (2 * W);
    for (int c = sg * 16; c < sg * 16 + 16; ++c) {
      const float* xc = xn + (size_t)c * HW;
      float s[4];
#pragma unroll
      for (int p = 0; p < 4; ++p) {
        s[p] = w00[p] * xc[o00[p]] + w01[p] * xc[o01[p]] +
               w10[p] * xc[o10[p]] + w11[p] * xc[o11[p]];
      }
      float* oc = outn + (size_t)c * (2 * H) * (2 * W);
      float2* r0 = (float2*)(oc + (size_t)(2 * y) * (2 * W) + 2 * xx);
      float2* r1 = (float2*)(oc + (size_t)(2 * y + 1) * (2 * W) + 2 * xx);
      *r0 = make_float2(s[0], s[1]);
      *r1 = make_float2(s[2], s[3]);
    }
  }
}

extern "C" void kernel_launch(void* const* d_in, const int* in_sizes, int n_in,
                              void* d_out, int out_size, void* d_ws, size_t ws_size,
                              hipStream_t stream) {
  const float* x = (const float*)d_in[0];
  const float* w = (const float*)d_in[1];
  const float* b = (const float*)d_in[2];
  float* out = (float*)d_out;

  const size_t xt_bytes = (size_t)NB * HW * C * sizeof(float);  // 32 MB
  const size_t wt_bytes = (size_t)8 * C * 9 * sizeof(float);    // 36 KB
  dim3 grid(NB * H * NSEG), block(256);

  if (d_ws != nullptr && ws_size >= xt_bytes + wt_bytes) {
    float* xt = (float*)d_ws;
    float* wt = (float*)((char*)d_ws + xt_bytes);
    prep_wt<<<dim3(36), block, 0, stream>>>(w, wt);
    transpose_nchw_nhwc<<<dim3(NB * (HW / TPX)), block, 0, stream>>>(x, xt);
    dcn_fused_t5<<<grid, block, 0, stream>>>(xt, wt, b, out);
  } else {
    dcn_fused<<<grid, block, 0, stream>>>(x, w, b, out);
  }
}

// Round 6
// 294.668 us; speedup vs baseline: 1.7798x; 1.7798x over previous
//
#include <hip/hip_runtime.h>

#define H 128
#define W 128
#define C 128
#define NB 4
#define HW (H * W)
#define PXB 32            // pixels per block (quarter row)
#define NSEG (W / PXB)    // 4
#define TPX 64            // pixels per transpose block

// ---------------------------------------------------------------------------
// Pre-pass 1: NCHW -> NHWC transpose of x into workspace (32 MB).
// ---------------------------------------------------------------------------
__global__ __launch_bounds__(256) void transpose_nchw_nhwc(
    const float* __restrict__ x, float* __restrict__ xt) {
  __shared__ float tile[TPX][C + 1];  // 64 x 129 floats = 33 KB
  const int blk = blockIdx.x;
  const int n = blk >> 8;                 // HW/TPX = 256 blocks per image
  const int p0 = (blk & 255) * TPX;
  const float* xn = x + (size_t)n * C * HW;
  float* xtn = xt + (size_t)n * HW * C;

  const int i = threadIdx.x & 63;         // pixel within tile
  const int c0 = threadIdx.x >> 6;        // 0..3
#pragma unroll
  for (int c = c0; c < C; c += 4)
    tile[i][c] = xn[(size_t)c * HW + p0 + i];
  __syncthreads();

  const int cl = threadIdx.x & 31;        // channel quad 0..31
  const int pr = threadIdx.x >> 5;        // 0..7
#pragma unroll
  for (int p = pr; p < TPX; p += 8) {
    float4 v = make_float4(tile[p][4 * cl + 0], tile[p][4 * cl + 1],
                           tile[p][4 * cl + 2], tile[p][4 * cl + 3]);
    *(float4*)(xtn + (size_t)(p0 + p) * C + 4 * cl) = v;
  }
}

// ---------------------------------------------------------------------------
// Pre-pass 2: weight re-layout wg[p][ch][k] -> wt[ch][k][p]  (9216 floats).
// ---------------------------------------------------------------------------
__global__ __launch_bounds__(256) void prep_wt(
    const float* __restrict__ wg, float* __restrict__ wt) {
  const int i = blockIdx.x * 256 + threadIdx.x;  // 36 blocks x 256 = 9216
  const int ch = i / 72;
  const int rem = i % 72;
  const int k = rem >> 3;
  const int p = rem & 7;
  wt[i] = wg[((size_t)p * C + ch) * 9 + k];
}

// ---------------------------------------------------------------------------
// Kernel A: offset conv + tap-table build (t3 phases 1/1.5/1.75, proven
// no-spill). Writes per-(px,pos) tap indices (premultiplied by C/4) and
// bilinear weights to workspace. LDS ~17.6 KB, no phase 2.
// ---------------------------------------------------------------------------
__global__ __launch_bounds__(256, 4) void dcn_offsets(
    const float* __restrict__ xt, const float* __restrict__ wt,
    const float* __restrict__ b, int4* __restrict__ tabi,
    float4* __restrict__ tabw) {

  __shared__ __align__(16) float lsh[4096];  // lacc [16][32][8]
  __shared__ float loff[PXB][9];

  const int t = threadIdx.x;
  const int bxr = blockIdx.x;
  const int bx = ((bxr & 7) << 8) | (bxr >> 3);  // XCD swizzle (2048 = 8*256)
  const int seg = bx & (NSEG - 1);
  const int y = (bx >> 2) & (H - 1);
  const int n = bx >> 9;
  const int x0 = seg * PXB;

  const float* xtn = xt + (size_t)n * HW * C;

  // ---------------- Phase 1: offset conv from NHWC (t3 verbatim) -----------
  {
    const int pp = t & 15;   // pixel pair -> pixels x0+2pp, x0+2pp+1
    const int cg = t >> 4;   // channel group 0..15 (8 channels each)
    const int xb = x0 + 2 * pp;
    const int cb = cg * 8;

    int xs[4];
    float colm[4];
#pragma unroll
    for (int j = 0; j < 4; ++j) {
      int xa = xb - 1 + j;
      colm[j] = ((unsigned)xa < (unsigned)W) ? 1.f : 0.f;
      xs[j] = xa < 0 ? 0 : (xa > W - 1 ? W - 1 : xa);
    }
    int pix[3][4];
    float m[3][4];
#pragma unroll
    for (int r = 0; r < 3; ++r) {
      int yy = y + r - 1;
      float rm = ((unsigned)yy < (unsigned)H) ? 1.f : 0.f;
      int yc = yy < 0 ? 0 : (yy > H - 1 ? H - 1 : yy);
#pragma unroll
      for (int j = 0; j < 4; ++j) {
        m[r][j] = rm * colm[j];
        pix[r][j] = yc * W + xs[j];
      }
    }

    float acc[2][8];
#pragma unroll
    for (int p = 0; p < 8; ++p) { acc[0][p] = 0.f; acc[1][p] = 0.f; }

#pragma unroll
    for (int c2 = 0; c2 < 2; ++c2) {
      float xvq[3][4][4];
#pragma unroll
      for (int r = 0; r < 3; ++r) {
#pragma unroll
        for (int j = 0; j < 4; ++j) {
          float4 v = *(const float4*)(xtn + (size_t)pix[r][j] * C + cb + c2 * 4);
          const float mm = m[r][j];
          xvq[r][j][0] = v.x * mm;
          xvq[r][j][1] = v.y * mm;
          xvq[r][j][2] = v.z * mm;
          xvq[r][j][3] = v.w * mm;
        }
      }
#pragma unroll
      for (int cc = 0; cc < 4; ++cc) {
        const int ch = cb + c2 * 4 + cc;
        const float4* wv4 = (const float4*)(wt + (size_t)ch * 72);
#pragma unroll
        for (int k = 0; k < 9; ++k) {
          const int r = k / 3, kw = k % 3;
          const float4 wa = wv4[2 * k];      // p = 0..3
          const float4 wb = wv4[2 * k + 1];  // p = 4..7
          const float xl = xvq[r][kw][cc];
          const float xr = xvq[r][kw + 1][cc];
          acc[0][0] += xl * wa.x; acc[0][1] += xl * wa.y;
          acc[0][2] += xl * wa.z; acc[0][3] += xl * wa.w;
          acc[0][4] += xl * wb.x; acc[0][5] += xl * wb.y;
          acc[0][6] += xl * wb.z; acc[0][7] += xl * wb.w;
          acc[1][0] += xr * wa.x; acc[1][1] += xr * wa.y;
          acc[1][2] += xr * wa.z; acc[1][3] += xr * wa.w;
          acc[1][4] += xr * wb.x; acc[1][5] += xr * wb.y;
          acc[1][6] += xr * wb.z; acc[1][7] += xr * wb.w;
        }
      }
    }
#pragma unroll
    for (int p = 0; p < 8; ++p) {
      lsh[((size_t)cg * PXB + 2 * pp) * 8 + p] = acc[0][p];
      lsh[((size_t)cg * PXB + 2 * pp + 1) * 8 + p] = acc[1][p];
    }
  }
  __syncthreads();

  // ---------------- Phase 1.5: reduce 16 groups + bias ---------------------
  {
    const int px = t >> 3;  // 0..31
    const int p = t & 7;
    float s = b[p];
#pragma unroll
    for (int g = 0; g < 16; ++g) s += lsh[((size_t)g * PXB + px) * 8 + p];
    loff[px][p] = s;
  }
  __syncthreads();

  // ---------------- Phase 1.75: tap table -> global ------------------------
  if (t < 128) {
    const int px = t >> 2;
    const int pos = t & 3;
    const int xx = x0 + px;
    float sy = (float)y + loff[px][2 * pos];
    float sx = (float)xx + loff[px][2 * pos + 1];
    float y0f = floorf(sy), x0f = floorf(sx);
    float wy1 = sy - y0f, wx1 = sx - x0f;
    float wy0 = 1.f - wy1, wx0 = 1.f - wx1;
    int iy0 = (int)y0f, ix0 = (int)x0f;
    int iy1 = iy0 + 1, ix1 = ix0 + 1;
    float vy0 = ((unsigned)iy0 < (unsigned)H) ? 1.f : 0.f;
    float vy1 = ((unsigned)iy1 < (unsigned)H) ? 1.f : 0.f;
    float vx0 = ((unsigned)ix0 < (unsigned)W) ? 1.f : 0.f;
    float vx1 = ((unsigned)ix1 < (unsigned)W) ? 1.f : 0.f;
    int cy0 = iy0 < 0 ? 0 : (iy0 > H - 1 ? H - 1 : iy0);
    int cy1 = iy1 < 0 ? 0 : (iy1 > H - 1 ? H - 1 : iy1);
    int cx0 = ix0 < 0 ? 0 : (ix0 > W - 1 ? W - 1 : ix0);
    int cx1 = ix1 < 0 ? 0 : (ix1 > W - 1 ? W - 1 : ix1);
    const size_t gp = ((size_t)(n * H + y) * W + xx) * 4 + pos;
    tabi[gp] = make_int4((cy0 * W + cx0) * (C / 4), (cy0 * W + cx1) * (C / 4),
                         (cy1 * W + cx0) * (C / 4), (cy1 * W + cx1) * (C / 4));
    tabw[gp] = make_float4(wy0 * wx0 * vy0 * vx0, wy0 * wx1 * vy0 * vx1,
                           wy1 * wx0 * vy1 * vx0, wy1 * wx1 * vy1 * vx1);
  }
}

// ---------------------------------------------------------------------------
// Kernel B: pure gather + direct 2x2 float4 stores. Zero LDS, zero barriers.
// 8192 blocks x 256 thr, XCD-swizzled. Thread = (px-pair, chan-quad, kh).
// ---------------------------------------------------------------------------
__global__ __launch_bounds__(256, 4) void dcn_sample(
    const float* __restrict__ xt, const int4* __restrict__ tabi,
    const float4* __restrict__ tabw, float* __restrict__ out) {
  const int braw = blockIdx.x;
  const int bk = ((braw & 7) << 10) | (braw >> 3);  // XCD swizzle (8192=8*1024)
  const int t = threadIdx.x;
  const int seg8 = bk & 15;            // 8-px group within the row
  const int y = (bk >> 4) & (H - 1);
  const int n = bk >> 11;
  const int pair2 = t & 3;
  const int q = (t >> 2) & 31;         // channel quad
  const int half = t >> 7;             // kh

  const float4* xt4n = (const float4*)xt + (size_t)n * HW * (C / 4);
  const size_t rowb = (size_t)(n * H + y) * W;

  float sc[2][2][4];
#pragma unroll
  for (int bb = 0; bb < 2; ++bb) {
#pragma unroll
    for (int pp2 = 0; pp2 < 2; ++pp2) {
      const int px = seg8 * 8 + 2 * pair2 + bb;
      const size_t gp = (rowb + px) * 4 + 2 * half + pp2;
      const int4 o = tabi[gp];
      const float4 wv = tabw[gp];
      const float4 v00 = xt4n[o.x + q];
      const float4 v01 = xt4n[o.y + q];
      const float4 v10 = xt4n[o.z + q];
      const float4 v11 = xt4n[o.w + q];
      sc[bb][pp2][0] = wv.x * v00.x + wv.y * v01.x + wv.z * v10.x + wv.w * v11.x;
      sc[bb][pp2][1] = wv.x * v00.y + wv.y * v01.y + wv.z * v10.y + wv.w * v11.y;
      sc[bb][pp2][2] = wv.x * v00.z + wv.y * v01.z + wv.z * v10.z + wv.w * v11.z;
      sc[bb][pp2][3] = wv.x * v00.w + wv.y * v01.w + wv.z * v10.w + wv.w * v11.w;
    }
  }

  float* obase = out + (size_t)n * C * 4 * HW +
                 (size_t)(2 * y + half) * (2 * W) + 16 * seg8 + 4 * pair2;
#pragma unroll
  for (int j = 0; j < 4; ++j) {
    *(float4*)(obase + (size_t)(4 * q + j) * (4 * HW)) =
        make_float4(sc[0][0][j], sc[0][1][j], sc[1][0][j], sc[1][1][j]);
  }
}

// ---------------------------------------------------------------------------
// Mid fallback: t3 fused kernel (proven 96.7 us), used if ws fits xt+wt only.
// ---------------------------------------------------------------------------
__global__ __launch_bounds__(256, 4) void dcn_fused_t3(
    const float* __restrict__ xt, const float* __restrict__ wt,
    const float* __restrict__ b, float* __restrict__ out) {

  __shared__ __align__(16) float lsh[4224];
  __shared__ float loff[PXB][9];
  __shared__ int4   ltapi[PXB][4];
  __shared__ float4 ltapw[PXB][4];

  const int t = threadIdx.x;
  const int bxr = blockIdx.x;
  const int bx = ((bxr & 7) << 8) | (bxr >> 3);
  const int seg = bx & (NSEG - 1);
  const int y = (bx >> 2) & (H - 1);
  const int n = bx >> 9;
  const int x0 = seg * PXB;

  const float* xtn = xt + (size_t)n * HW * C;

  {
    const int pp = t & 15;
    const int cg = t >> 4;
    const int xb = x0 + 2 * pp;
    const int cb = cg * 8;

    int xs[4];
    float colm[4];
#pragma unroll
    for (int j = 0; j < 4; ++j) {
      int xa = xb - 1 + j;
      colm[j] = ((unsigned)xa < (unsigned)W) ? 1.f : 0.f;
      xs[j] = xa < 0 ? 0 : (xa > W - 1 ? W - 1 : xa);
    }
    int pix[3][4];
    float m[3][4];
#pragma unroll
    for (int r = 0; r < 3; ++r) {
      int yy = y + r - 1;
      float rm = ((unsigned)yy < (unsigned)H) ? 1.f : 0.f;
      int yc = yy < 0 ? 0 : (yy > H - 1 ? H - 1 : yy);
#pragma unroll
      for (int j = 0; j < 4; ++j) {
        m[r][j] = rm * colm[j];
        pix[r][j] = yc * W + xs[j];
      }
    }

    float acc[2][8];
#pragma unroll
    for (int p = 0; p < 8; ++p) { acc[0][p] = 0.f; acc[1][p] = 0.f; }

#pragma unroll
    for (int c2 = 0; c2 < 2; ++c2) {
      float xvq[3][4][4];
#pragma unroll
      for (int r = 0; r < 3; ++r) {
#pragma unroll
        for (int j = 0; j < 4; ++j) {
          float4 v = *(const float4*)(xtn + (size_t)pix[r][j] * C + cb + c2 * 4);
          const float mm = m[r][j];
          xvq[r][j][0] = v.x * mm;
          xvq[r][j][1] = v.y * mm;
          xvq[r][j][2] = v.z * mm;
          xvq[r][j][3] = v.w * mm;
        }
      }
#pragma unroll
      for (int cc = 0; cc < 4; ++cc) {
        const int ch = cb + c2 * 4 + cc;
        const float4* wv4 = (const float4*)(wt + (size_t)ch * 72);
#pragma unroll
        for (int k = 0; k < 9; ++k) {
          const int r = k / 3, kw = k % 3;
          const float4 wa = wv4[2 * k];
          const float4 wb = wv4[2 * k + 1];
          const float xl = xvq[r][kw][cc];
          const float xr = xvq[r][kw + 1][cc];
          acc[0][0] += xl * wa.x; acc[0][1] += xl * wa.y;
          acc[0][2] += xl * wa.z; acc[0][3] += xl * wa.w;
          acc[0][4] += xl * wb.x; acc[0][5] += xl * wb.y;
          acc[0][6] += xl * wb.z; acc[0][7] += xl * wb.w;
          acc[1][0] += xr * wa.x; acc[1][1] += xr * wa.y;
          acc[1][2] += xr * wa.z; acc[1][3] += xr * wa.w;
          acc[1][4] += xr * wb.x; acc[1][5] += xr * wb.y;
          acc[1][6] += xr * wb.z; acc[1][7] += xr * wb.w;
        }
      }
    }
#pragma unroll
    for (int p = 0; p < 8; ++p) {
      lsh[((size_t)cg * PXB + 2 * pp) * 8 + p] = acc[0][p];
      lsh[((size_t)cg * PXB + 2 * pp + 1) * 8 + p] = acc[1][p];
    }
  }
  __syncthreads();

  {
    const int px = t >> 3;
    const int p = t & 7;
    float s = b[p];
#pragma unroll
    for (int g = 0; g < 16; ++g) s += lsh[((size_t)g * PXB + px) * 8 + p];
    loff[px][p] = s;
  }
  __syncthreads();

  if (t < 128) {
    const int px = t >> 2;
    const int pos = t & 3;
    const int xx = x0 + px;
    float sy = (float)y + loff[px][2 * pos];
    float sx = (float)xx + loff[px][2 * pos + 1];
    float y0f = floorf(sy), x0f = floorf(sx);
    float wy1 = sy - y0f, wx1 = sx - x0f;
    float wy0 = 1.f - wy1, wx0 = 1.f - wx1;
    int iy0 = (int)y0f, ix0 = (int)x0f;
    int iy1 = iy0 + 1, ix1 = ix0 + 1;
    float vy0 = ((unsigned)iy0 < (unsigned)H) ? 1.f : 0.f;
    float vy1 = ((unsigned)iy1 < (unsigned)H) ? 1.f : 0.f;
    float vx0 = ((unsigned)ix0 < (unsigned)W) ? 1.f : 0.f;
    float vx1 = ((unsigned)ix1 < (unsigned)W) ? 1.f : 0.f;
    int cy0 = iy0 < 0 ? 0 : (iy0 > H - 1 ? H - 1 : iy0);
    int cy1 = iy1 < 0 ? 0 : (iy1 > H - 1 ? H - 1 : iy1);
    int cx0 = ix0 < 0 ? 0 : (ix0 > W - 1 ? W - 1 : ix0);
    int cx1 = ix1 < 0 ? 0 : (ix1 > W - 1 ? W - 1 : ix1);
    ltapi[px][pos] = make_int4(cy0 * W + cx0, cy0 * W + cx1,
                               cy1 * W + cx0, cy1 * W + cx1);
    ltapw[px][pos] = make_float4(wy0 * wx0 * vy0 * vx0, wy0 * wx1 * vy0 * vx1,
                                 wy1 * wx0 * vy1 * vx0, wy1 * wx1 * vy1 * vx1);
  }
  __syncthreads();

  {
    const int cq = t & 31;
    const int pg = t >> 5;
    const int spx = t & 7;
    const int cg4 = t >> 3;
    const float4* xt4 = (const float4*)xtn;
    float4* lout4 = (float4*)lsh;
    float* outn = out + (size_t)n * C * (2 * H) * (2 * W);

    for (int pass = 0; pass < 4; ++pass) {
      const int px = pass * 8 + pg;
      float4 sacc[4];
#pragma unroll
      for (int pos = 0; pos < 4; ++pos) {
        const int4 o = ltapi[px][pos];
        const float4 wv = ltapw[px][pos];
        float4 v00 = xt4[(size_t)o.x * (C / 4) + cq];
        float4 v01 = xt4[(size_t)o.y * (C / 4) + cq];
        float4 v10 = xt4[(size_t)o.z * (C / 4) + cq];
        float4 v11 = xt4[(size_t)o.w * (C / 4) + cq];
        sacc[pos].x = wv.x * v00.x + wv.y * v01.x + wv.z * v10.x + wv.w * v11.x;
        sacc[pos].y = wv.x * v00.y + wv.y * v01.y + wv.z * v10.y + wv.w * v11.y;
        sacc[pos].z = wv.x * v00.z + wv.y * v01.z + wv.z * v10.z + wv.w * v11.z;
        sacc[pos].w = wv.x * v00.w + wv.y * v01.w + wv.z * v10.w + wv.w * v11.w;
      }
      __syncthreads();
#pragma unroll
      for (int pos = 0; pos < 4; ++pos)
        lout4[(pos * 8 + pg) * 33 + cq] = sacc[pos];
      __syncthreads();

      float4 v[4];
#pragma unroll
      for (int pos = 0; pos < 4; ++pos)
        v[pos] = lout4[(pos * 8 + spx) * 33 + cg4];
      const int xg = x0 + pass * 8 + spx;
      float* obase = outn + (size_t)(2 * y) * (2 * W) + 2 * xg;
#define STORE_CH(J, CMP)                                                      \
      {                                                                       \
        float* oc = obase + (size_t)(cg4 * 4 + J) * (4 * HW);                 \
        *(float2*)oc = make_float2(v[0].CMP, v[1].CMP);                       \
        *(float2*)(oc + 2 * W) = make_float2(v[2].CMP, v[3].CMP);             \
      }
      STORE_CH(0, x) STORE_CH(1, y) STORE_CH(2, z) STORE_CH(3, w)
#undef STORE_CH
    }
  }
}

// ---------------------------------------------------------------------------
// Last-resort fallback: original NCHW-gather kernel (ws too small for xt).
// ---------------------------------------------------------------------------
__global__ __launch_bounds__(256) void dcn_fused(
    const float* __restrict__ x, const float* __restrict__ wg,
    const float* __restrict__ b, float* __restrict__ out) {

  __shared__ float lacc[16][PXB][8];
  __shared__ float loff[PXB][9];

  const int t = threadIdx.x;
  const int bx = blockIdx.x;
  const int seg = bx & (NSEG - 1);
  const int y = (bx >> 2) & (H - 1);
  const int n = bx >> 9;
  const int x0 = seg * PXB;

  const float* xn = x + (size_t)n * C * HW;

  {
    const int pp = t & 15;
    const int cg = t >> 4;
    const int xb = x0 + 2 * pp;

    int xs[4];
    float colm[4];
#pragma unroll
    for (int j = 0; j < 4; ++j) {
      int xa = xb - 1 + j;
      colm[j] = ((unsigned)xa < (unsigned)W) ? 1.f : 0.f;
      xs[j] = xa < 0 ? 0 : (xa > W - 1 ? W - 1 : xa);
    }
    int rowo[3];
    float m[3][4];
#pragma unroll
    for (int r = 0; r < 3; ++r) {
      int yy = y + r - 1;
      float rm = ((unsigned)yy < (unsigned)H) ? 1.f : 0.f;
      int yc = yy < 0 ? 0 : (yy > H - 1 ? H - 1 : yy);
      rowo[r] = yc * W;
#pragma unroll
      for (int j = 0; j < 4; ++j) m[r][j] = rm * colm[j];
    }

    float acc[2][8];
#pragma unroll
    for (int p = 0; p < 8; ++p) { acc[0][p] = 0.f; acc[1][p] = 0.f; }

    for (int c = 0; c < 8; ++c) {
      const int ch = cg * 8 + c;
      const float* xc = xn + (size_t)ch * HW;
      float xv[3][4];
#pragma unroll
      for (int r = 0; r < 3; ++r)
#pragma unroll
        for (int j = 0; j < 4; ++j)
          xv[r][j] = xc[rowo[r] + xs[j]] * m[r][j];

      const float* wc = wg + (size_t)ch * 9;
#pragma unroll
      for (int p = 0; p < 8; ++p) {
        const float* wp = wc + (size_t)p * C * 9;
#pragma unroll
        for (int r = 0; r < 3; ++r) {
#pragma unroll
          for (int kw = 0; kw < 3; ++kw) {
            const float wv = wp[r * 3 + kw];
            acc[0][p] += xv[r][kw] * wv;
            acc[1][p] += xv[r][kw + 1] * wv;
          }
        }
      }
    }
#pragma unroll
    for (int p = 0; p < 8; ++p) {
      lacc[cg][2 * pp][p] = acc[0][p];
      lacc[cg][2 * pp + 1][p] = acc[1][p];
    }
  }
  __syncthreads();

  {
    const int px = t >> 3;
    const int p = t & 7;
    float s = b[p];
#pragma unroll
    for (int g = 0; g < 16; ++g) s += lacc[g][px][p];
    loff[px][p] = s;
  }
  __syncthreads();

  {
    const int px = t & (PXB - 1);
    const int sg = t >> 5;
    const int xx = x0 + px;

    float offv[8];
#pragma unroll
    for (int q = 0; q < 8; ++q) offv[q] = loff[px][q];

    int o00[4], o01[4], o10[4], o11[4];
    float w00[4], w01[4], w10[4], w11[4];
#pragma unroll
    for (int p = 0; p < 4; ++p) {
      float sy = (float)y + offv[2 * p];
      float sx = (float)xx + offv[2 * p + 1];
      float y0f = floorf(sy), x0f = floorf(sx);
      float wy1 = sy - y0f, wx1 = sx - x0f;
      float wy0 = 1.f - wy1, wx0 = 1.f - wx1;
      int iy0 = (int)y0f, ix0 = (int)x0f;
      int iy1 = iy0 + 1, ix1 = ix0 + 1;
      float vy0 = ((unsigned)iy0 < (unsigned)H) ? 1.f : 0.f;
      float vy1 = ((unsigned)iy1 < (unsigned)H) ? 1.f : 0.f;
      float vx0 = ((unsigned)ix0 < (unsigned)W) ? 1.f : 0.f;
      float vx1 = ((unsigned)ix1 < (unsigned)W) ? 1.f : 0.f;
      int cy0 = iy0 < 0 ? 0 : (iy0 > H - 1 ? H - 1 : iy0);
      int cy1 = iy1 < 0 ? 0 : (iy1 > H - 1 ? H - 1 : iy1);
      int cx0 = ix0 < 0 ? 0 : (ix0 > W - 1 ? W - 1 : ix0);
      int cx1 = ix1 < 0 ? 0 : (ix1 > W - 1 ? W - 1 : ix1);
      o00[p] = cy0 * W + cx0; o01[p] = cy0 * W + cx1;
      o10[p] = cy1 * W + cx0; o11[p] = cy1 * W + cx1;
      w00[p] = wy0 * wx0 * vy0 * vx0;
      w01[p] = wy0 * wx1 * vy0 * vx1;
      w10[p] = wy1 * wx0 * vy1 * vx0;
      w11[p] = wy1 * wx1 * vy1 * vx1;
    }

    float* outn = out + (size_t)n * C * (2 * H) * (2 * W);
    for (int c = sg * 16; c < sg * 16 + 16; ++c) {
      const float* xc = xn + (size_t)c * HW;
      float s[4];
#pragma unroll
      for (int p = 0; p < 4; ++p) {
        s[p] = w00[p] * xc[o00[p]] + w01[p] * xc[o01[p]] +
               w10[p] * xc[o10[p]] + w11[p] * xc[o11[p]];
      }
      float* oc = outn + (size_t)c * (2 * H) * (2 * W);
      float2* r0 = (float2*)(oc + (size_t)(2 * y) * (2 * W) + 2 * xx);
      float2* r1 = (float2*)(oc + (size_t)(2 * y + 1) * (2 * W) + 2 * xx);
      *r0 = make_float2(s[0], s[1]);
      *r1 = make_float2(s[2], s[3]);
    }
  }
}

extern "C" void kernel_launch(void* const* d_in, const int* in_sizes, int n_in,
                              void* d_out, int out_size, void* d_ws, size_t ws_size,
                              hipStream_t stream) {
  const float* x = (const float*)d_in[0];
  const float* w = (const float*)d_in[1];
  const float* b = (const float*)d_in[2];
  float* out = (float*)d_out;

  const size_t xt_bytes = (size_t)NB * HW * C * sizeof(float);   // 32 MB
  const size_t wt_bytes = (size_t)8 * C * 9 * sizeof(float);     // 36 KB
  const size_t tab_cnt = (size_t)NB * HW * 4;                    // 256 K entries
  const size_t tabi_bytes = tab_cnt * sizeof(int4);              // 4 MB
  const size_t tabw_bytes = tab_cnt * sizeof(float4);            // 4 MB
  dim3 block(256);

  if (d_ws != nullptr && ws_size >= xt_bytes + wt_bytes + tabi_bytes + tabw_bytes) {
    float* xt = (float*)d_ws;
    float* wt = (float*)((char*)d_ws + xt_bytes);
    int4* tabi = (int4*)((char*)d_ws + xt_bytes + wt_bytes);
    float4* tabw = (float4*)((char*)d_ws + xt_bytes + wt_bytes + tabi_bytes);
    prep_wt<<<dim3(36), block, 0, stream>>>(w, wt);
    transpose_nchw_nhwc<<<dim3(NB * (HW / TPX)), block, 0, stream>>>(x, xt);
    dcn_offsets<<<dim3(NB * H * NSEG), block, 0, stream>>>(xt, wt, b, tabi, tabw);
    dcn_sample<<<dim3(NB * H * 16), block, 0, stream>>>(xt, tabi, tabw, out);
  } else if (d_ws != nullptr && ws_size >= xt_bytes + wt_bytes) {
    float* xt = (float*)d_ws;
    float* wt = (float*)((char*)d_ws + xt_bytes);
    prep_wt<<<dim3(36), block, 0, stream>>>(w, wt);
    transpose_nchw_nhwc<<<dim3(NB * (HW / TPX)), block, 0, stream>>>(x, xt);
    dcn_fused_t3<<<dim3(NB * H * NSEG), block, 0, stream>>>(xt, wt, b, out);
  } else {
    dcn_fused<<<dim3(NB * H * NSEG), block, 0, stream>>>(x, w, b, out);
  }
}

// Round 7
// 248.072 us; speedup vs baseline: 2.1141x; 1.1878x over previous
//
#include <hip/hip_runtime.h>

#define H 128
#define W 128
#define C 128
#define NB 4
#define HW (H * W)
#define PXB 32            // pixels per block (quarter row)
#define NSEG (W / PXB)    // 4
#define TPX 64            // pixels per transpose block
#define SPX 120           // max staged pixels per block
#define CMAX 40           // max staged window cols
#define PSTR 132          // staged pixel stride in floats (128 + 4: bank spread)

// ---------------------------------------------------------------------------
// Pre-pass 1: NCHW -> NHWC transpose of x into workspace (32 MB).
// ---------------------------------------------------------------------------
__global__ __launch_bounds__(256) void transpose_nchw_nhwc(
    const float* __restrict__ x, float* __restrict__ xt) {
  __shared__ float tile[TPX][C + 1];  // 64 x 129 floats = 33 KB
  const int blk = blockIdx.x;
  const int n = blk >> 8;                 // HW/TPX = 256 blocks per image
  const int p0 = (blk & 255) * TPX;
  const float* xn = x + (size_t)n * C * HW;
  float* xtn = xt + (size_t)n * HW * C;

  const int i = threadIdx.x & 63;         // pixel within tile
  const int c0 = threadIdx.x >> 6;        // 0..3
#pragma unroll
  for (int c = c0; c < C; c += 4)
    tile[i][c] = xn[(size_t)c * HW + p0 + i];
  __syncthreads();

  const int cl = threadIdx.x & 31;        // channel quad 0..31
  const int pr = threadIdx.x >> 5;        // 0..7
#pragma unroll
  for (int p = pr; p < TPX; p += 8) {
    float4 v = make_float4(tile[p][4 * cl + 0], tile[p][4 * cl + 1],
                           tile[p][4 * cl + 2], tile[p][4 * cl + 3]);
    *(float4*)(xtn + (size_t)(p0 + p) * C + 4 * cl) = v;
  }
}

// ---------------------------------------------------------------------------
// Pre-pass 2: weight re-layout wg[p][ch][k] -> wt[ch][k][p]  (9216 floats).
// ---------------------------------------------------------------------------
__global__ __launch_bounds__(256) void prep_wt(
    const float* __restrict__ wg, float* __restrict__ wt) {
  const int i = blockIdx.x * 256 + threadIdx.x;  // 36 blocks x 256 = 9216
  const int ch = i / 72;
  const int rem = i % 72;
  const int k = rem >> 3;
  const int p = rem & 7;
  wt[i] = wg[((size_t)p * C + ch) * 9 + k];
}

// ---------------------------------------------------------------------------
// Fused deformable-conv t6:
//  Phases 1/1.5/1.75 = t3 verbatim (proven no-spill conv + tap tables).
//  NEW: per-block tap bounding box -> stage the source window into LDS once
//  (each 64B line read ONCE, coalesced) -> gather via ds_read_b128 with
//  per-tap global fallback for taps outside the (clipped) window.
//  Stores = round-6 dcn_sample's direct full-line float4 pattern (proven).
//  LDS ~69 KB -> 2 blocks/CU; conv overlaps gather across resident blocks.
// ---------------------------------------------------------------------------
__global__ __launch_bounds__(256, 2) void dcn_fused_t6(
    const float* __restrict__ xt, const float* __restrict__ wt,
    const float* __restrict__ b, float* __restrict__ out) {

  __shared__ __align__(16) float lstage[SPX * PSTR];  // 63360 B; aliases lacc
  __shared__ float loff[PXB][9];
  __shared__ int4   ltapi[PXB][4];   // raw clamped pixel indices (iy*W+ix)
  __shared__ float4 ltapw[PXB][4];   // bilinear weights (validity folded in)
  __shared__ int lred[4][4];         // per-wave bbox partials
  __shared__ int lwin[4];            // py0, px0w, Rrows, Ccols

  const int t = threadIdx.x;
  const int bxr = blockIdx.x;
  const int bx = ((bxr & 7) << 8) | (bxr >> 3);  // XCD swizzle (2048 = 8*256)
  const int seg = bx & (NSEG - 1);
  const int y = (bx >> 2) & (H - 1);
  const int n = bx >> 9;
  const int x0 = seg * PXB;

  const float* xtn = xt + (size_t)n * HW * C;

  // ---------------- Phase 1: offset conv from NHWC (t3 verbatim) -----------
  {
    const int pp = t & 15;   // pixel pair -> pixels x0+2pp, x0+2pp+1
    const int cg = t >> 4;   // channel group 0..15 (8 channels each)
    const int xb = x0 + 2 * pp;
    const int cb = cg * 8;

    int xs[4];
    float colm[4];
#pragma unroll
    for (int j = 0; j < 4; ++j) {
      int xa = xb - 1 + j;
      colm[j] = ((unsigned)xa < (unsigned)W) ? 1.f : 0.f;
      xs[j] = xa < 0 ? 0 : (xa > W - 1 ? W - 1 : xa);
    }
    int pix[3][4];
    float m[3][4];
#pragma unroll
    for (int r = 0; r < 3; ++r) {
      int yy = y + r - 1;
      float rm = ((unsigned)yy < (unsigned)H) ? 1.f : 0.f;
      int yc = yy < 0 ? 0 : (yy > H - 1 ? H - 1 : yy);
#pragma unroll
      for (int j = 0; j < 4; ++j) {
        m[r][j] = rm * colm[j];
        pix[r][j] = yc * W + xs[j];
      }
    }

    float acc[2][8];
#pragma unroll
    for (int p = 0; p < 8; ++p) { acc[0][p] = 0.f; acc[1][p] = 0.f; }

#pragma unroll
    for (int c2 = 0; c2 < 2; ++c2) {
      float xvq[3][4][4];
#pragma unroll
      for (int r = 0; r < 3; ++r) {
#pragma unroll
        for (int j = 0; j < 4; ++j) {
          float4 v = *(const float4*)(xtn + (size_t)pix[r][j] * C + cb + c2 * 4);
          const float mm = m[r][j];
          xvq[r][j][0] = v.x * mm;
          xvq[r][j][1] = v.y * mm;
          xvq[r][j][2] = v.z * mm;
          xvq[r][j][3] = v.w * mm;
        }
      }
#pragma unroll
      for (int cc = 0; cc < 4; ++cc) {
        const int ch = cb + c2 * 4 + cc;
        const float4* wv4 = (const float4*)(wt + (size_t)ch * 72);
#pragma unroll
        for (int k = 0; k < 9; ++k) {
          const int r = k / 3, kw = k % 3;
          const float4 wa = wv4[2 * k];      // p = 0..3
          const float4 wb = wv4[2 * k + 1];  // p = 4..7
          const float xl = xvq[r][kw][cc];
          const float xr = xvq[r][kw + 1][cc];
          acc[0][0] += xl * wa.x; acc[0][1] += xl * wa.y;
          acc[0][2] += xl * wa.z; acc[0][3] += xl * wa.w;
          acc[0][4] += xl * wb.x; acc[0][5] += xl * wb.y;
          acc[0][6] += xl * wb.z; acc[0][7] += xl * wb.w;
          acc[1][0] += xr * wa.x; acc[1][1] += xr * wa.y;
          acc[1][2] += xr * wa.z; acc[1][3] += xr * wa.w;
          acc[1][4] += xr * wb.x; acc[1][5] += xr * wb.y;
          acc[1][6] += xr * wb.z; acc[1][7] += xr * wb.w;
        }
      }
    }
#pragma unroll
    for (int p = 0; p < 8; ++p) {
      lstage[((size_t)cg * PXB + 2 * pp) * 8 + p] = acc[0][p];
      lstage[((size_t)cg * PXB + 2 * pp + 1) * 8 + p] = acc[1][p];
    }
  }
  __syncthreads();

  // ---------------- Phase 1.5: reduce 16 groups + bias ---------------------
  {
    const int px = t >> 3;  // 0..31
    const int p = t & 7;
    float s = b[p];
#pragma unroll
    for (int g = 0; g < 16; ++g) s += lstage[((size_t)g * PXB + px) * 8 + p];
    loff[px][p] = s;
  }
  __syncthreads();

  // ---------------- Phase 1.75: tap table + bbox ---------------------------
  {
    int ymin = H, ymax = 0, xmin = W, xmax = 0;
    if (t < 128) {
      const int px = t >> 2;
      const int pos = t & 3;
      const int xx = x0 + px;
      float sy = (float)y + loff[px][2 * pos];
      float sx = (float)xx + loff[px][2 * pos + 1];
      float y0f = floorf(sy), x0f = floorf(sx);
      float wy1 = sy - y0f, wx1 = sx - x0f;
      float wy0 = 1.f - wy1, wx0 = 1.f - wx1;
      int iy0 = (int)y0f, ix0 = (int)x0f;
      int iy1 = iy0 + 1, ix1 = ix0 + 1;
      float vy0 = ((unsigned)iy0 < (unsigned)H) ? 1.f : 0.f;
      float vy1 = ((unsigned)iy1 < (unsigned)H) ? 1.f : 0.f;
      float vx0 = ((unsigned)ix0 < (unsigned)W) ? 1.f : 0.f;
      float vx1 = ((unsigned)ix1 < (unsigned)W) ? 1.f : 0.f;
      int cy0 = iy0 < 0 ? 0 : (iy0 > H - 1 ? H - 1 : iy0);
      int cy1 = iy1 < 0 ? 0 : (iy1 > H - 1 ? H - 1 : iy1);
      int cx0 = ix0 < 0 ? 0 : (ix0 > W - 1 ? W - 1 : ix0);
      int cx1 = ix1 < 0 ? 0 : (ix1 > W - 1 ? W - 1 : ix1);
      ltapi[px][pos] = make_int4(cy0 * W + cx0, cy0 * W + cx1,
                                 cy1 * W + cx0, cy1 * W + cx1);
      ltapw[px][pos] = make_float4(wy0 * wx0 * vy0 * vx0, wy0 * wx1 * vy0 * vx1,
                                   wy1 * wx0 * vy1 * vx0, wy1 * wx1 * vy1 * vx1);
      ymin = cy0; ymax = cy1; xmin = cx0 < cx1 ? cx0 : cx1;
      xmax = cx0 > cx1 ? cx0 : cx1;
    }
    // full-wave butterfly reduce (waves 2,3 carry neutral values)
#pragma unroll
    for (int d = 1; d < 64; d <<= 1) {
      int v;
      v = __shfl_xor(ymin, d); ymin = v < ymin ? v : ymin;
      v = __shfl_xor(ymax, d); ymax = v > ymax ? v : ymax;
      v = __shfl_xor(xmin, d); xmin = v < xmin ? v : xmin;
      v = __shfl_xor(xmax, d); xmax = v > xmax ? v : xmax;
    }
    if ((t & 63) == 0) {
      const int wv = t >> 6;
      lred[wv][0] = ymin; lred[wv][1] = ymax;
      lred[wv][2] = xmin; lred[wv][3] = xmax;
    }
    __syncthreads();
    if (t == 0) {
      int py0 = lred[0][0] < lred[1][0] ? lred[0][0] : lred[1][0];
      int py1 = lred[0][1] > lred[1][1] ? lred[0][1] : lred[1][1];
      int qx0 = lred[0][2] < lred[1][2] ? lred[0][2] : lred[1][2];
      int qx1 = lred[0][3] > lred[1][3] ? lred[0][3] : lred[1][3];
      int cols = qx1 - qx0 + 1;
      if (cols > CMAX) cols = CMAX;
      int rows = py1 - py0 + 1;
      int rmax = SPX / cols;
      if (rows > rmax) rows = rmax;
      lwin[0] = py0; lwin[1] = qx0; lwin[2] = rows; lwin[3] = cols;
    }
    __syncthreads();
  }

  // ---------------- Phase 1.9: stage source window into LDS ----------------
  const int py0 = lwin[0], qx0 = lwin[1], Rr = lwin[2], Cc = lwin[3];
  const float4* xt4 = (const float4*)xtn;
  {
    const int nf = Cc * 32;  // float4s per staged row
#pragma unroll 1
    for (int r = 0; r < Rr; ++r) {
      const float4* src = xt4 + (size_t)((py0 + r) * W + qx0) * 32;
      for (int i = t; i < nf; i += 256) {
        const int c = i >> 5, quad = i & 31;
        *(float4*)&lstage[(r * Cc + c) * PSTR + 4 * quad] = src[i];
      }
    }
  }
  __syncthreads();

  // ---------------- Phase 2: LDS gather -> direct full-line stores ---------
  {
    const int pair = t & 3;
    const int q = (t >> 2) & 31;   // channel quad
    const int half = t >> 7;       // kh
    float* outn = out + (size_t)n * C * 4 * HW;

#pragma unroll 1
    for (int pass = 0; pass < 4; ++pass) {
      const int px0p = pass * 8 + 2 * pair;
      float sc[2][2][4];
#pragma unroll
      for (int bb = 0; bb < 2; ++bb) {
#pragma unroll
        for (int pp2 = 0; pp2 < 2; ++pp2) {
          const int pos = 2 * half + pp2;
          const int4 o = ltapi[px0p + bb][pos];
          const float4 wv = ltapw[px0p + bb][pos];
          float4 tv[4];
          const int oo[4] = {o.x, o.y, o.z, o.w};
#pragma unroll
          for (int j = 0; j < 4; ++j) {
            const int idx = oo[j];
            const int rr = (idx >> 7) - py0;
            const int cc2 = (idx & 127) - qx0;
            if ((unsigned)rr < (unsigned)Rr && (unsigned)cc2 < (unsigned)Cc)
              tv[j] = *(const float4*)&lstage[(rr * Cc + cc2) * PSTR + 4 * q];
            else
              tv[j] = xt4[(size_t)idx * 32 + q];
          }
          sc[bb][pp2][0] = wv.x * tv[0].x + wv.y * tv[1].x + wv.z * tv[2].x + wv.w * tv[3].x;
          sc[bb][pp2][1] = wv.x * tv[0].y + wv.y * tv[1].y + wv.z * tv[2].y + wv.w * tv[3].y;
          sc[bb][pp2][2] = wv.x * tv[0].z + wv.y * tv[1].z + wv.z * tv[2].z + wv.w * tv[3].z;
          sc[bb][pp2][3] = wv.x * tv[0].w + wv.y * tv[1].w + wv.z * tv[2].w + wv.w * tv[3].w;
        }
      }
      float* obase = outn + (size_t)(2 * y + half) * (2 * W) + 2 * (x0 + px0p);
#pragma unroll
      for (int j = 0; j < 4; ++j) {
        *(float4*)(obase + (size_t)(4 * q + j) * (4 * HW)) =
            make_float4(sc[0][0][j], sc[0][1][j], sc[1][0][j], sc[1][1][j]);
      }
    }
  }
}

// ---------------------------------------------------------------------------
// Fallback: original NCHW-gather kernel (used only if workspace too small).
// ---------------------------------------------------------------------------
__global__ __launch_bounds__(256) void dcn_fused(
    const float* __restrict__ x, const float* __restrict__ wg,
    const float* __restrict__ b, float* __restrict__ out) {

  __shared__ float lacc[16][PXB][8];
  __shared__ float loff[PXB][9];

  const int t = threadIdx.x;
  const int bx = blockIdx.x;
  const int seg = bx & (NSEG - 1);
  const int y = (bx >> 2) & (H - 1);
  const int n = bx >> 9;
  const int x0 = seg * PXB;

  const float* xn = x + (size_t)n * C * HW;

  {
    const int pp = t & 15;
    const int cg = t >> 4;
    const int xb = x0 + 2 * pp;

    int xs[4];
    float colm[4];
#pragma unroll
    for (int j = 0; j < 4; ++j) {
      int xa = xb - 1 + j;
      colm[j] = ((unsigned)xa < (unsigned)W) ? 1.f : 0.f;
      xs[j] = xa < 0 ? 0 : (xa > W - 1 ? W - 1 : xa);
    }
    int rowo[3];
    float m[3][4];
#pragma unroll
    for (int r = 0; r < 3; ++r) {
      int yy = y + r - 1;
      float rm = ((unsigned)yy < (unsigned)H) ? 1.f : 0.f;
      int yc = yy < 0 ? 0 : (yy > H - 1 ? H - 1 : yy);
      rowo[r] = yc * W;
#pragma unroll
      for (int j = 0; j < 4; ++j) m[r][j] = rm * colm[j];
    }

    float acc[2][8];
#pragma unroll
    for (int p = 0; p < 8; ++p) { acc[0][p] = 0.f; acc[1][p] = 0.f; }

    for (int c = 0; c < 8; ++c) {
      const int ch = cg * 8 + c;
      const float* xc = xn + (size_t)ch * HW;
      float xv[3][4];
#pragma unroll
      for (int r = 0; r < 3; ++r)
#pragma unroll
        for (int j = 0; j < 4; ++j)
          xv[r][j] = xc[rowo[r] + xs[j]] * m[r][j];

      const float* wc = wg + (size_t)ch * 9;
#pragma unroll
      for (int p = 0; p < 8; ++p) {
        const float* wp = wc + (size_t)p * C * 9;
#pragma unroll
        for (int r = 0; r < 3; ++r) {
#pragma unroll
          for (int kw = 0; kw < 3; ++kw) {
            const float wv = wp[r * 3 + kw];
            acc[0][p] += xv[r][kw] * wv;
            acc[1][p] += xv[r][kw + 1] * wv;
          }
        }
      }
    }
#pragma unroll
    for (int p = 0; p < 8; ++p) {
      lacc[cg][2 * pp][p] = acc[0][p];
      lacc[cg][2 * pp + 1][p] = acc[1][p];
    }
  }
  __syncthreads();

  {
    const int px = t >> 3;
    const int p = t & 7;
    float s = b[p];
#pragma unroll
    for (int g = 0; g < 16; ++g) s += lacc[g][px][p];
    loff[px][p] = s;
  }
  __syncthreads();

  {
    const int px = t & (PXB - 1);
    const int sg = t >> 5;
    const int xx = x0 + px;

    float offv[8];
#pragma unroll
    for (int q = 0; q < 8; ++q) offv[q] = loff[px][q];

    int o00[4], o01[4], o10[4], o11[4];
    float w00[4], w01[4], w10[4], w11[4];
#pragma unroll
    for (int p = 0; p < 4; ++p) {
      float sy = (float)y + offv[2 * p];
      float sx = (float)xx + offv[2 * p + 1];
      float y0f = floorf(sy), x0f = floorf(sx);
      float wy1 = sy - y0f, wx1 = sx - x0f;
      float wy0 = 1.f - wy1, wx0 = 1.f - wx1;
      int iy0 = (int)y0f, ix0 = (int)x0f;
      int iy1 = iy0 + 1, ix1 = ix0 + 1;
      float vy0 = ((unsigned)iy0 < (unsigned)H) ? 1.f : 0.f;
      float vy1 = ((unsigned)iy1 < (unsigned)H) ? 1.f : 0.f;
      float vx0 = ((unsigned)ix0 < (unsigned)W) ? 1.f : 0.f;
      float vx1 = ((unsigned)ix1 < (unsigned)W) ? 1.f : 0.f;
      int cy0 = iy0 < 0 ? 0 : (iy0 > H - 1 ? H - 1 : iy0);
      int cy1 = iy1 < 0 ? 0 : (iy1 > H - 1 ? H - 1 : iy1);
      int cx0 = ix0 < 0 ? 0 : (ix0 > W - 1 ? W - 1 : ix0);
      int cx1 = ix1 < 0 ? 0 : (ix1 > W - 1 ? W - 1 : ix1);
      o00[p] = cy0 * W + cx0; o01[p] = cy0 * W + cx1;
      o10[p] = cy1 * W + cx0; o11[p] = cy1 * W + cx1;
      w00[p] = wy0 * wx0 * vy0 * vx0;
      w01[p] = wy0 * wx1 * vy0 * vx1;
      w10[p] = wy1 * wx0 * vy1 * vx0;
      w11[p] = wy1 * wx1 * vy1 * vx1;
    }

    float* outn = out + (size_t)n * C * (2 * H) * (2 * W);
    for (int c = sg * 16; c < sg * 16 + 16; ++c) {
      const float* xc = xn + (size_t)c * HW;
      float s[4];
#pragma unroll
      for (int p = 0; p < 4; ++p) {
        s[p] = w00[p] * xc[o00[p]] + w01[p] * xc[o01[p]] +
               w10[p] * xc[o10[p]] + w11[p] * xc[o11[p]];
      }
      float* oc = outn + (size_t)c * (2 * H) * (2 * W);
      float2* r0 = (float2*)(oc + (size_t)(2 * y) * (2 * W) + 2 * xx);
      float2* r1 = (float2*)(oc + (size_t)(2 * y + 1) * (2 * W) + 2 * xx);
      *r0 = make_float2(s[0], s[1]);
      *r1 = make_float2(s[2], s[3]);
    }
  }
}

extern "C" void kernel_launch(void* const* d_in, const int* in_sizes, int n_in,
                              void* d_out, int out_size, void* d_ws, size_t ws_size,
                              hipStream_t stream) {
  const float* x = (const float*)d_in[0];
  const float* w = (const float*)d_in[1];
  const float* b = (const float*)d_in[2];
  float* out = (float*)d_out;

  const size_t xt_bytes = (size_t)NB * HW * C * sizeof(float);   // 32 MB
  const size_t wt_bytes = (size_t)8 * C * 9 * sizeof(float);     // 36 KB
  dim3 block(256);

  if (d_ws != nullptr && ws_size >= xt_bytes + wt_bytes) {
    float* xt = (float*)d_ws;
    float* wt = (float*)((char*)d_ws + xt_bytes);
    prep_wt<<<dim3(36), block, 0, stream>>>(w, wt);
    transpose_nchw_nhwc<<<dim3(NB * (HW / TPX)), block, 0, stream>>>(x, xt);
    dcn_fused_t6<<<dim3(NB * H * NSEG), block, 0, stream>>>(xt, wt, b, out);
  } else {
    dcn_fused<<<dim3(NB * H * NSEG), block, 0, stream>>>(x, w, b, out);
  }
}